// Round 4
// baseline (384.537 us; speedup 1.0000x reference)
//
#include <hip/hip_runtime.h>

#define FARD 1e10f
#define EPSV 1e-10f

typedef float fx4 __attribute__((ext_vector_type(4)));

__device__ __forceinline__ fx4 ntload4(const float* p) {
    return __builtin_nontemporal_load(reinterpret_cast<const fx4*>(p));
}

// One ray per 8-lane segment; each lane owns 8 consecutive samples.
// All global loads are nontemporal float4 (streaming, read-once data).
__global__ __launch_bounds__(256) void nerf_render_kernel(
    const float* __restrict__ sigmas,   // (N, 64)
    const float* __restrict__ rgbs,     // (N, 64, 3)
    const float* __restrict__ z_vals,   // (N, 64)
    float* __restrict__ out,            // [rgb 3N | depth N | accum N]
    int n_rays)
{
    const int tid = blockIdx.x * blockDim.x + threadIdx.x;
    const int ray = tid >> 3;
    if (ray >= n_rays) return;
    const int l = threadIdx.x & 7;      // lane within 8-lane segment

    // ---- loads (10x nontemporal float4 per lane, issued up front) ----
    const float* sp = sigmas + (size_t)ray * 64 + l * 8;
    const float* zp = z_vals + (size_t)ray * 64 + l * 8;
    const float* cp = rgbs   + (size_t)ray * 192 + l * 24;
    const fx4 s0 = ntload4(sp), s1 = ntload4(sp + 4);
    const fx4 z0 = ntload4(zp), z1 = ntload4(zp + 4);
    const fx4 c0 = ntload4(cp),      c1 = ntload4(cp + 4),  c2 = ntload4(cp + 8);
    const fx4 c3 = ntload4(cp + 12), c4 = ntload4(cp + 16), c5 = ntload4(cp + 20);

    const float zz[8] = {z0.x, z0.y, z0.z, z0.w, z1.x, z1.y, z1.z, z1.w};
    const float sv[8] = {s0.x, s0.y, s0.z, s0.w, s1.x, s1.y, s1.z, s1.w};
    const float cc[24] = {c0.x, c0.y, c0.z, c0.w, c1.x, c1.y, c1.z, c1.w,
                          c2.x, c2.y, c2.z, c2.w, c3.x, c3.y, c3.z, c3.w,
                          c4.x, c4.y, c4.z, c4.w, c5.x, c5.y, c5.z, c5.w};

    // z of next lane's first sample (sample 8l+8); unused garbage at l==7
    const float zn = __shfl_down(z0.x, 1, 8);

    float d[8];
    #pragma unroll
    for (int k = 0; k < 7; ++k) d[k] = zz[k + 1] - zz[k];
    d[7] = (l == 7) ? FARD : (zn - zz[7]);

    // ---- lane-local pass: u_k = alpha_k * prod_{j<k} t_j ----
    // (t = e + eps == 1 - alpha + eps exactly, since e = exp(-relu(s)*d))
    float run = 1.f;     // running product of t within the lane
    float P6  = 1.f;     // product t0..t6 of this lane (valid use at l==7)
    float Wp = 0.f, Dp = 0.f, Rp = 0.f, Gp = 0.f, Bp = 0.f;
    #pragma unroll
    for (int k = 0; k < 8; ++k) {
        const float e = __expf(-fmaxf(sv[k], 0.f) * d[k]);
        const float u = (1.f - e) * run;
        if (k == 7) P6 = run;
        run *= (e + EPSV);
        Wp += u;
        Dp += u * zz[k];
        Rp += u * cc[3 * k + 0];
        Gp += u * cc[3 * k + 1];
        Bp += u * cc[3 * k + 2];
    }

    // ---- exclusive prefix product of lane products over 8 lanes ----
    float scan = run;
    #pragma unroll
    for (int off = 1; off < 8; off <<= 1) {
        const float v = __shfl_up(scan, off, 8);
        if (l >= off) scan *= v;
    }
    float ex = __shfl_up(scan, 1, 8);
    if (l == 0) ex = 1.f;

    // ---- scale partials, butterfly-reduce over the 8-lane segment ----
    float wsum = ex * Wp;
    float dsum = ex * Dp;
    float rsum = ex * Rp;
    float gsum = ex * Gp;
    float bsum = ex * Bp;
    #pragma unroll
    for (int off = 4; off >= 1; off >>= 1) {
        wsum += __shfl_xor(wsum, off, 8);
        dsum += __shfl_xor(dsum, off, 8);
        rsum += __shfl_xor(rsum, off, 8);
        gsum += __shfl_xor(gsum, off, 8);
        bsum += __shfl_xor(bsum, off, 8);
    }

    // ---- writes (all lanes hold the sums; spread for coalescing) ----
    const float bg = 1.f - wsum;
    if (l < 3) {
        const float v = (l == 0) ? rsum : ((l == 1) ? gsum : bsum);
        out[(size_t)ray * 3 + l] = v + bg;
    } else if (l == 3) {
        out[(size_t)3 * n_rays + ray] = dsum;
    } else if (l == 7) {
        out[(size_t)4 * n_rays + ray] = ex * P6;   // accum_trans[:, -1]
    }
}

extern "C" void kernel_launch(void* const* d_in, const int* in_sizes, int n_in,
                              void* d_out, int out_size, void* d_ws, size_t ws_size,
                              hipStream_t stream) {
    const float* sigmas = (const float*)d_in[0];
    const float* rgbs   = (const float*)d_in[1];
    const float* z_vals = (const float*)d_in[2];
    float* out = (float*)d_out;

    const int n_rays = in_sizes[0] / 64;
    const int threads = 256;
    const long long total_threads = (long long)n_rays * 8;
    const int blocks = (int)((total_threads + threads - 1) / threads);

    nerf_render_kernel<<<blocks, threads, 0, stream>>>(sigmas, rgbs, z_vals, out, n_rays);
}

// Round 5
// 264.263 us; speedup vs baseline: 1.4551x; 1.4551x over previous
//
#include <hip/hip_runtime.h>

#define FARD 1e10f
#define EPSV 1e-10f

struct RayData {
    float4 s0, s1, z0, z1, c0, c1, c2, c3, c4, c5;
};

__device__ __forceinline__ void loadRay(RayData& r,
                                        const float* __restrict__ sigmas,
                                        const float* __restrict__ rgbs,
                                        const float* __restrict__ z_vals,
                                        int ray, int l) {
    const float4* sp = reinterpret_cast<const float4*>(sigmas + (size_t)ray * 64 + l * 8);
    const float4* zp = reinterpret_cast<const float4*>(z_vals + (size_t)ray * 64 + l * 8);
    const float4* cp = reinterpret_cast<const float4*>(rgbs   + (size_t)ray * 192 + l * 24);
    r.s0 = sp[0]; r.s1 = sp[1];
    r.z0 = zp[0]; r.z1 = zp[1];
    r.c0 = cp[0]; r.c1 = cp[1]; r.c2 = cp[2];
    r.c3 = cp[3]; r.c4 = cp[4]; r.c5 = cp[5];
}

__device__ __forceinline__ void processRay(const RayData& rd,
                                           float* __restrict__ out,
                                           int ray, int l, int n_rays) {
    const float zz[8] = {rd.z0.x, rd.z0.y, rd.z0.z, rd.z0.w,
                         rd.z1.x, rd.z1.y, rd.z1.z, rd.z1.w};
    const float sv[8] = {rd.s0.x, rd.s0.y, rd.s0.z, rd.s0.w,
                         rd.s1.x, rd.s1.y, rd.s1.z, rd.s1.w};
    const float cc[24] = {rd.c0.x, rd.c0.y, rd.c0.z, rd.c0.w,
                          rd.c1.x, rd.c1.y, rd.c1.z, rd.c1.w,
                          rd.c2.x, rd.c2.y, rd.c2.z, rd.c2.w,
                          rd.c3.x, rd.c3.y, rd.c3.z, rd.c3.w,
                          rd.c4.x, rd.c4.y, rd.c4.z, rd.c4.w,
                          rd.c5.x, rd.c5.y, rd.c5.z, rd.c5.w};

    // z of next lane's first sample (sample 8l+8); garbage at l==7 (unused)
    const float zn = __shfl_down(rd.z0.x, 1, 8);

    float d[8];
    #pragma unroll
    for (int k = 0; k < 7; ++k) d[k] = zz[k + 1] - zz[k];
    d[7] = (l == 7) ? FARD : (zn - zz[7]);

    // lane-local: u_k = alpha_k * prod_{j<k} t_j   (t = e + eps)
    float run = 1.f, P6 = 1.f;
    float Wp = 0.f, Dp = 0.f, Rp = 0.f, Gp = 0.f, Bp = 0.f;
    #pragma unroll
    for (int k = 0; k < 8; ++k) {
        const float e = __expf(-fmaxf(sv[k], 0.f) * d[k]);
        const float u = (1.f - e) * run;
        if (k == 7) P6 = run;
        run *= (e + EPSV);
        Wp += u;
        Dp += u * zz[k];
        Rp += u * cc[3 * k + 0];
        Gp += u * cc[3 * k + 1];
        Bp += u * cc[3 * k + 2];
    }

    // exclusive prefix product of lane products over the 8-lane segment
    float scan = run;
    #pragma unroll
    for (int off = 1; off < 8; off <<= 1) {
        const float v = __shfl_up(scan, off, 8);
        if (l >= off) scan *= v;
    }
    float ex = __shfl_up(scan, 1, 8);
    if (l == 0) ex = 1.f;

    float wsum = ex * Wp, dsum = ex * Dp;
    float rsum = ex * Rp, gsum = ex * Gp, bsum = ex * Bp;
    #pragma unroll
    for (int off = 4; off >= 1; off >>= 1) {
        wsum += __shfl_xor(wsum, off, 8);
        dsum += __shfl_xor(dsum, off, 8);
        rsum += __shfl_xor(rsum, off, 8);
        gsum += __shfl_xor(gsum, off, 8);
        bsum += __shfl_xor(bsum, off, 8);
    }

    const float bg = 1.f - wsum;
    if (l < 3) {
        const float v = (l == 0) ? rsum : ((l == 1) ? gsum : bsum);
        out[(size_t)ray * 3 + l] = v + bg;
    } else if (l == 3) {
        out[(size_t)3 * n_rays + ray] = dsum;
    } else if (l == 7) {
        out[(size_t)4 * n_rays + ray] = ex * P6;   // accum_trans[:, -1]
    }
}

// 8 lanes per ray, 8 samples per lane; grid-stride over rays with explicit
// register double-buffering so next ray's 10 loads are in flight during
// the current ray's compute.
__global__ __launch_bounds__(256) void nerf_render_kernel(
    const float* __restrict__ sigmas,
    const float* __restrict__ rgbs,
    const float* __restrict__ z_vals,
    float* __restrict__ out,
    int n_rays)
{
    const int l = threadIdx.x & 7;
    const int T = gridDim.x * blockDim.x;          // total threads
    const int nseg = n_rays * 8;                   // one segment == one thread-slot

    int sA = blockIdx.x * blockDim.x + threadIdx.x;
    if (sA >= nseg) return;

    RayData A, B;
    loadRay(A, sigmas, rgbs, z_vals, sA >> 3, l);
    int sB = sA + T;

    #pragma unroll 1
    while (sB < nseg) {
        loadRay(B, sigmas, rgbs, z_vals, sB >> 3, l);
        processRay(A, out, sA >> 3, l, n_rays);
        sA = sB + T;
        if (sA >= nseg) {
            processRay(B, out, sB >> 3, l, n_rays);
            return;
        }
        loadRay(A, sigmas, rgbs, z_vals, sA >> 3, l);
        processRay(B, out, sB >> 3, l, n_rays);
        sB = sA + T;
    }
    processRay(A, out, sA >> 3, l, n_rays);
}

extern "C" void kernel_launch(void* const* d_in, const int* in_sizes, int n_in,
                              void* d_out, int out_size, void* d_ws, size_t ws_size,
                              hipStream_t stream) {
    const float* sigmas = (const float*)d_in[0];
    const float* rgbs   = (const float*)d_in[1];
    const float* z_vals = (const float*)d_in[2];
    float* out = (float*)d_out;

    const int n_rays = in_sizes[0] / 64;
    const int threads = 256;
    const int blocks = 2048;   // ~8 blocks/CU; each thread handles ~16 rays

    nerf_render_kernel<<<blocks, threads, 0, stream>>>(sigmas, rgbs, z_vals, out, n_rays);
}